// Round 12
// baseline (159.777 us; speedup 1.0000x reference)
//
#include <hip/hip_runtime.h>
#include <cfloat>
#include <climits>

#define BATCH 4
#define KQ    2048
#define NP    4096
#define CIN   64
#define CMID  32
#define NB    16
#define NBINS 2048   // bits >> 20 : 8 exp bits + 3 mantissa bits
#define CANDCAP 256
#define QPB   8      // queries per block in edge_prep (2 sequential per wave)

typedef short   bf16x8  __attribute__((ext_vector_type(8)));
typedef float   floatx4 __attribute__((ext_vector_type(4)));

__device__ __forceinline__ unsigned short f2bf(float f) {
  unsigned u = __float_as_uint(f);
  u = (u + 0x7fffu + ((u >> 16) & 1u)) >> 16;   // RNE, inputs finite
  return (unsigned short)u;
}
__device__ __forceinline__ float bf2f(unsigned short u) {
  return __uint_as_float((unsigned)u << 16);
}

// async global->LDS, 16B per lane; LDS dst = base + lane*16 (wave-uniform base)
__device__ __forceinline__ void load_lds16(const void* g, void* l) {
  __builtin_amdgcn_global_load_lds(
      (const __attribute__((address_space(1))) unsigned int*)g,
      (__attribute__((address_space(3))) unsigned int*)l, 16, 0, 0);
}

// ---------------------------------------------------------------------------
// Kernel 1 (R26): block-per-query radix-select top-16 (R25 structure:
// 32-lane parallel boundary refine). R26 change: the fc0/fc1 weight
// transposes (f32 [K][N] -> bf16 [N][K]) are folded into the TAIL of blocks
// 0..543 here (8192-block grid has ~32 sequential blocks/CU of slack)
// instead of the head of edge_prep's 1024-block grid (where they stretched
// the critical tail). Conditional barriers are block-uniform (bid test).
// 8 KB u32 hist (2048 bins, bits>>20), two-level scan, rank pass. Set-only
// semantics; boundary ties -> lower index.
// ---------------------------------------------------------------------------
__global__ __launch_bounds__(256, 8) void select_topk(
    const float* __restrict__ keys, const float* __restrict__ points,
    const float* __restrict__ fc0_W, const float* __restrict__ fc1_W,
    unsigned short* __restrict__ W0T, unsigned short* __restrict__ W1T,
    int* __restrict__ nidx_g) {
  __shared__ __align__(16) int hist[NBINS];   // 8 KB
  __shared__ int   psum[256];
  __shared__ float cand_d[CANDCAP];
  __shared__ int   cand_i[CANDCAP];
  __shared__ int   nidx[NB];
  __shared__ int   sel_cnt, cand_cnt, sBin, sCbelow;
  __shared__ float tt[32][33];                // 4.2 KB (transpose staging)

  const int tid = threadIdx.x;
  const int b   = blockIdx.x >> 11;

#pragma unroll
  for (int t = 0; t < 2; ++t)
    *reinterpret_cast<int4*>(&hist[(tid + t * 256) * 4]) = int4{0, 0, 0, 0};
  if (tid == 0) { sel_cnt = 0; cand_cnt = 0; }

  const float kx = keys[blockIdx.x * 3 + 0];
  const float ky = keys[blockIdx.x * 3 + 1];
  const float kz = keys[blockIdx.x * 3 + 2];
  __syncthreads();

  // distances in 4 chunks of 4 points (3 float4 live at a time) + histogram
  const float4* pv =
      reinterpret_cast<const float4*>(points + (size_t)b * NP * 3) + (size_t)tid * 12;
  float dreg[16];
#pragma unroll
  for (int g = 0; g < 4; ++g) {
    const float4 v0 = pv[g * 3 + 0];
    const float4 v1 = pv[g * 3 + 1];
    const float4 v2 = pv[g * 3 + 2];
    const float px[4] = {v0.x, v0.w, v1.z, v2.y};
    const float py[4] = {v0.y, v1.x, v1.w, v2.z};
    const float pz[4] = {v0.z, v1.y, v2.x, v2.w};
#pragma unroll
    for (int j = 0; j < 4; ++j) {
      const float dx = px[j] - kx, dy = py[j] - ky, dz = pz[j] - kz;
      const float d  = dx * dx + dy * dy + dz * dz;
      dreg[g * 4 + j] = d;
      atomicAdd(&hist[__float_as_uint(d) >> 20], 1);
    }
  }
  __syncthreads();

  // two-level threshold scan: per-thread 8-bin sums -> wave-0 shuffle scan
  {
    const int base = tid * 8;
    int s = 0;
#pragma unroll
    for (int t = 0; t < 2; ++t) {
      const int4 hv = *reinterpret_cast<const int4*>(&hist[base + t * 4]);
      s += hv.x + hv.y + hv.z + hv.w;
    }
    psum[tid] = s;
  }
  __syncthreads();

  if (tid < 64) {
    // group tid covers bins [tid*32, tid*32+32)
    const int q4 = psum[tid * 4] + psum[tid * 4 + 1] + psum[tid * 4 + 2] + psum[tid * 4 + 3];
    int incl = q4;
#pragma unroll
    for (int off = 1; off < 64; off <<= 1) {
      int u = __shfl_up(incl, off);
      if (tid >= off) incl += u;
    }
    const unsigned long long bal = __ballot(incl >= NB);
    const int bl = __ffsll((long long)bal) - 1;               // boundary group
    const int cum_before = __shfl(incl, bl) - __shfl(q4, bl); // cum before group

    // parallel refine: lanes 0..31 scan the group's 32 bins
    const int hv = (tid < 32) ? hist[bl * 32 + tid] : 0;
    int hincl = hv;
#pragma unroll
    for (int off = 1; off < 32; off <<= 1) {
      int u = __shfl_up(hincl, off);
      if (tid >= off) hincl += u;
    }
    const unsigned long long bal2 =
        __ballot(tid < 32 && (cum_before + hincl >= NB));
    const int bo = __ffsll((long long)bal2) - 1;
    if (tid == bo) {
      sBin = bl * 32 + bo;
      sCbelow = cum_before + hincl - hv;   // exclusive prefix at boundary bin
    }
  }
  __syncthreads();

  const unsigned B = (unsigned)sBin;
#pragma unroll
  for (int j = 0; j < 16; ++j) {
    const int i = tid * 16 + j;
    const unsigned bk = __float_as_uint(dreg[j]) >> 20;
    if (bk < B) {
      int pos = atomicAdd(&sel_cnt, 1);
      nidx[pos] = i;
    } else if (bk == B) {
      int pos = atomicAdd(&cand_cnt, 1);
      if (pos < CANDCAP) { cand_d[pos] = dreg[j]; cand_i[pos] = i; }
    }
  }
  __syncthreads();

  // boundary-bin rank pass: rank(j) = #{k: (d_k,i_k) < (d_j,i_j)}
  {
    const int rem = NB - sCbelow;
    const int cc  = min(cand_cnt, CANDCAP);
    for (int j = tid; j < cc; j += 256) {
      const float dj = cand_d[j]; const int ij = cand_i[j];
      int rank = 0;
      for (int k = 0; k < cc; ++k) {
        const float dk = cand_d[k]; const int ik = cand_i[k];
        rank += (dk < dj || (dk == dj && ik < ij)) ? 1 : 0;
      }
      if (rank < rem) nidx[sCbelow + rank] = ij;
    }
  }
  __syncthreads();

  if (tid < NB) nidx_g[blockIdx.x * NB + tid] = nidx[tid];

  // ---- folded weight transposes, tail of blocks 0..543 (block-uniform) ----
  if (blockIdx.x < 544) {
    const int bid = blockIdx.x;
    const float* W; unsigned short* WT; int K, N, k0, n0;
    if (bid < 512) { W = fc0_W; WT = W0T; K = 2048; N = 256;
                     k0 = (bid >> 3) * 32; n0 = (bid & 7) * 32; }
    else           { W = fc1_W; WT = W1T; K = 256;  N = 128;
                     k0 = ((bid - 512) >> 2) * 32; n0 = ((bid - 512) & 3) * 32; }
    const int tx = tid & 31, ty = tid >> 5;
    __syncthreads();   // nidx/LDS reads above complete before tt reuse window
#pragma unroll
    for (int p = 0; p < 4; ++p)
      tt[ty + p * 8][tx] = W[(size_t)(k0 + ty + p * 8) * N + n0 + tx];
    __syncthreads();
#pragma unroll
    for (int p = 0; p < 4; ++p)
      WT[(size_t)(n0 + ty + p * 8) * K + k0 + tx] = f2bf(tt[tx][ty + p * 8]);
  }
}

// ---------------------------------------------------------------------------
// Kernel 2 (R26 = R25 minus transposes): edge MLP + aggregation on MFMA,
// 2 queries per WAVE with `#pragma unroll 1`. B1/B2 weight fragments loaded
// once per wave. Per-query pipeline identical to R17: h1 in A-frag layout,
// h2/m/e via 12 mfma_16x16x32, no block barriers in main path.
// ---------------------------------------------------------------------------
__global__ __launch_bounds__(256) void edge_prep(
    const float* __restrict__ keys, const float* __restrict__ points,
    const float* __restrict__ feats, const int* __restrict__ nidx_g,
    const float* __restrict__ wc0_W, const float* __restrict__ wc0_b,
    const float* __restrict__ wc1_W, const float* __restrict__ wc1_b,
    const float* __restrict__ wc2_W, const float* __restrict__ wc2_b,
    unsigned short* __restrict__ E) {
  // per-wave slab: h2s [16][40 us] (80B rows) | ms [32][24 us] (48B rows)
  //              | fsT [64][24 us] (48B rows)  = 1280+1536+3072 = 5888 B
  __shared__ __align__(16) char smem[4 * 5888];   // 23 KB

  const int tid = threadIdx.x;
  const int bid = blockIdx.x;
  const int q0  = bid * QPB;

  const int wv   = tid >> 6, lane = tid & 63;
  const int s    = lane & 15, g = lane >> 4;

  unsigned short* h2s = reinterpret_cast<unsigned short*>(smem + wv * 5888);
  unsigned short* ms  = reinterpret_cast<unsigned short*>(smem + wv * 5888 + 1280);
  unsigned short* fsT = reinterpret_cast<unsigned short*>(smem + wv * 5888 + 2816);

  // ---- static B-fragments for W1, W2 (loaded once, reused for 2 queries) ----
  bf16x8 B1[2], B2[2];
#pragma unroll
  for (int t = 0; t < 2; ++t) {
#pragma unroll
    for (int e = 0; e < 8; ++e) {
      const int k = 8 * g + e, c = s + 16 * t;
      B1[t][e] = (short)f2bf(wc1_W[k * 32 + c]);
      B2[t][e] = (short)f2bf(wc2_W[k * 32 + c]);
    }
  }

  const floatx4 zc = {0.f, 0.f, 0.f, 0.f};

#pragma unroll 1
  for (int ep = 0; ep < 2; ++ep) {
    const int q = q0 + wv * 2 + ep;
    const int b = q >> 11;

    // ---- h1 (VALU, directly in A-frag layout) ----
    const int idx = nidx_g[q * NB + s];
    const float* p = points + ((size_t)b * NP + idx) * 3;
    const float kx = keys[q * 3], ky = keys[q * 3 + 1], kz = keys[q * 3 + 2];
    const float rx = p[0] - kx, ry = p[1] - ky, rz = p[2] - kz;
    bf16x8 A1;
#pragma unroll
    for (int e = 0; e < 8; ++e) {
      const int j = 8 * g + e;
      float h = rx * wc0_W[j] + ry * wc0_W[32 + j] + rz * wc0_W[64 + j] + wc0_b[j];
      A1[e] = (short)f2bf(fmaxf(h, 0.f));
    }

    // ---- h2 = relu(h1 @ W1 + b1) -> h2s[edge][j] (transpose via LDS) ----
#pragma unroll
    for (int t = 0; t < 2; ++t) {
      floatx4 d = __builtin_amdgcn_mfma_f32_16x16x32_bf16(A1, B1[t], zc, 0, 0, 0);
      const float bv = wc1_b[s + 16 * t];
#pragma unroll
      for (int r = 0; r < 4; ++r)
        h2s[(g * 4 + r) * 40 + 16 * t + s] = f2bf(fmaxf(d[r] + bv, 0.f));
    }

    // ---- A2 fragment: h2[edge=s][j=8g+e] ----
    const bf16x8 A2 = *reinterpret_cast<const bf16x8*>(&h2s[s * 40 + g * 8]);

    // ---- m = h2 @ W2 + b2 -> ms[mid][n] (packed b64) ----
#pragma unroll
    for (int t = 0; t < 2; ++t) {
      floatx4 d = __builtin_amdgcn_mfma_f32_16x16x32_bf16(A2, B2[t], zc, 0, 0, 0);
      const float bv = wc2_b[s + 16 * t];
      ushort4 o;
      o.x = f2bf(d[0] + bv); o.y = f2bf(d[1] + bv);
      o.z = f2bf(d[2] + bv); o.w = f2bf(d[3] + bv);
      *reinterpret_cast<ushort4*>(&ms[(16 * t + s) * 24 + g * 4]) = o;
    }

    // ---- stage neighbor features: fsT[ch][n] bf16 ----
#pragma unroll
    for (int t = 0; t < 4; ++t) {
      const int chunk = g + 4 * t;          // 0..15, ch0 = chunk*4
      const int n = s;
      const int idx_n = nidx_g[q * NB + n];
      const float4 v = *reinterpret_cast<const float4*>(
          feats + ((size_t)b * NP + idx_n) * CIN + chunk * 4);
      fsT[(chunk * 4 + 0) * 24 + n] = f2bf(v.x);
      fsT[(chunk * 4 + 1) * 24 + n] = f2bf(v.y);
      fsT[(chunk * 4 + 2) * 24 + n] = f2bf(v.z);
      fsT[(chunk * 4 + 3) * 24 + n] = f2bf(v.w);
    }

    // ---- e = f^T @ m : D[ch][mid], K=16 zero-padded to 32 ----
    bf16x8 fA[4], mB[2];
    const bf16x8 zf = {};
    if (lane < 32) {
#pragma unroll
      for (int ct = 0; ct < 4; ++ct)
        fA[ct] = *reinterpret_cast<const bf16x8*>(&fsT[(ct * 16 + s) * 24 + g * 8]);
#pragma unroll
      for (int mt = 0; mt < 2; ++mt)
        mB[mt] = *reinterpret_cast<const bf16x8*>(&ms[(mt * 16 + s) * 24 + g * 8]);
    } else {
#pragma unroll
      for (int ct = 0; ct < 4; ++ct) fA[ct] = zf;
#pragma unroll
      for (int mt = 0; mt < 2; ++mt) mB[mt] = zf;
    }

    unsigned short* Eq = E + (size_t)q * 2048;
#pragma unroll
    for (int mt = 0; mt < 2; ++mt) {
#pragma unroll
      for (int ct = 0; ct < 4; ++ct) {
        floatx4 d = __builtin_amdgcn_mfma_f32_16x16x32_bf16(fA[ct], mB[mt], zc, 0, 0, 0);
        ushort4 o;
        o.x = f2bf(d[0]); o.y = f2bf(d[1]); o.z = f2bf(d[2]); o.w = f2bf(d[3]);
        // mid = 16*mt + s (col), ch = 16*ct + 4*g + r (rows, contiguous)
        *reinterpret_cast<ushort4*>(&Eq[(16 * mt + s) * 64 + ct * 16 + g * 4]) = o;
      }
    }
  }
}

// ---------------------------------------------------------------------------
// Kernel 3/4: MFMA GEMM  C = act(A[M,KDIM]bf16 @ Bt[N,KDIM]^T + bias)
// 64x64 tile (4 waves x 32x32), BK=128, global_load_lds width-16 staging,
// XOR chunk swizzle for conflict-free ds_read_b128. SWIZZLE=true: an
// E-slab's 4 n-tiles land temporally adjacent on one XCD. R15: 2-phase
// double-buffered LDS; one barrier per K-iter.
// ---------------------------------------------------------------------------
template <int KDIM, bool RELU, bool OUTBF16, bool SWIZZLE>
__global__ __launch_bounds__(256) void gemm_mfma(
    const unsigned short* __restrict__ A,   // [M][KDIM] bf16
    const unsigned short* __restrict__ Bt,  // [N][KDIM] bf16
    const float* __restrict__ bias,
    void* __restrict__ Cout, int ldc) {
  __shared__ __align__(16) unsigned short Al[2][64 * 128];  // 32 KB
  __shared__ __align__(16) unsigned short Bl[2][64 * 128];  // 32 KB
  const int tid  = threadIdx.x;
  int m0, n0;
  if (SWIZZLE) {
    const int L    = blockIdx.x;
    const int slot = L >> 3;
    m0 = ((L & 7) * 16 + (slot >> 2)) * 64;
    n0 = (slot & 3) * 64;
  } else {
    m0 = blockIdx.x * 64;
    n0 = blockIdx.y * 64;
  }
  const int wv   = tid >> 6, lane = tid & 63;
  const int quad = lane >> 4, s = lane & 15;
  const int moff = (wv & 1) * 32, noff = (wv >> 1) * 32;
  const int lr   = lane >> 4, lc = lane & 15;

  floatx4 acc[2][2] = {{{0.f,0.f,0.f,0.f},{0.f,0.f,0.f,0.f}},
                       {{0.f,0.f,0.f,0.f},{0.f,0.f,0.f,0.f}}};

  auto stage = [&](int buf, int k0) {
#pragma unroll
    for (int t = 0; t < 4; ++t) {
      const int R0 = wv * 16 + t * 4;          // wave-uniform base row
      const int r  = R0 + lr;
      const int gc = lc ^ (r & 7);
      load_lds16(A  + (size_t)(m0 + r) * KDIM + k0 + gc * 8, &Al[buf][R0 * 128]);
      load_lds16(Bt + (size_t)(n0 + r) * KDIM + k0 + gc * 8, &Bl[buf][R0 * 128]);
    }
  };

  auto compute = [&](int buf) {
#pragma unroll
    for (int h = 0; h < 4; ++h) {
      bf16x8 af[2], bfr[2];
#pragma unroll
      for (int i = 0; i < 2; ++i) {
        const int r = moff + i * 16 + s;
        af[i] = *reinterpret_cast<const bf16x8*>(
            &Al[buf][(size_t)r * 128 + ((((h << 2) | quad) ^ (r & 7)) << 3)]);
      }
#pragma unroll
      for (int j = 0; j < 2; ++j) {
        const int r = noff + j * 16 + s;
        bfr[j] = *reinterpret_cast<const bf16x8*>(
            &Bl[buf][(size_t)r * 128 + ((((h << 2) | quad) ^ (r & 7)) << 3)]);
      }
#pragma unroll
      for (int i = 0; i < 2; ++i)
#pragma unroll
        for (int j = 0; j < 2; ++j)
          acc[i][j] = __builtin_amdgcn_mfma_f32_16x16x32_bf16(af[i], bfr[j], acc[i][j], 0, 0, 0);
    }
  };

  constexpr int NT = KDIM / 128;

  stage(0, 0);
  __syncthreads();
  int cur = 0;
#pragma unroll 1
  for (int it = 0; it < NT - 1; ++it) {
    stage(cur ^ 1, (it + 1) * 128);
    compute(cur);
    __syncthreads();
    cur ^= 1;
  }
  compute(cur);

#pragma unroll
  for (int i = 0; i < 2; ++i)
#pragma unroll
    for (int j = 0; j < 2; ++j) {
      const int col = n0 + noff + j * 16 + s;
      const float bv = bias[col];
#pragma unroll
      for (int r = 0; r < 4; ++r) {
        const int row = m0 + moff + i * 16 + quad * 4 + r;
        float v = acc[i][j][r] + bv;
        if (RELU) v = fmaxf(v, 0.f);
        if (OUTBF16)
          ((unsigned short*)Cout)[(size_t)row * ldc + col] = f2bf(v);
        else
          ((float*)Cout)[(size_t)row * ldc + col] = v;
      }
    }
}

// ---------------------------------------------------------------------------
extern "C" void kernel_launch(void* const* d_in, const int* in_sizes, int n_in,
                              void* d_out, int out_size, void* d_ws, size_t ws_size,
                              hipStream_t stream) {
  const float* keys   = (const float*)d_in[0];
  const float* points = (const float*)d_in[1];
  const float* feats  = (const float*)d_in[2];
  const float* wc0_W  = (const float*)d_in[3];
  const float* wc0_b  = (const float*)d_in[4];
  const float* wc1_W  = (const float*)d_in[5];
  const float* wc1_b  = (const float*)d_in[6];
  const float* wc2_W  = (const float*)d_in[7];
  const float* wc2_b  = (const float*)d_in[8];
  const float* fc0_W  = (const float*)d_in[9];
  const float* fc0_b  = (const float*)d_in[10];
  const float* fc1_W  = (const float*)d_in[11];
  const float* fc1_b  = (const float*)d_in[12];
  float* out = (float*)d_out;

  const int M = BATCH * KQ;   // 8192
  char* ws = (char*)d_ws;
  unsigned short* E    = (unsigned short*)(ws);                    // 32 MB
  unsigned short* H16  = (unsigned short*)(ws + (size_t)33554432); //  4 MB
  unsigned short* W0T  = (unsigned short*)(ws + (size_t)37748736); //  1 MB
  unsigned short* W1T  = (unsigned short*)(ws + (size_t)38797312); // 64 KB
  int*            nidx = (int*)(ws + (size_t)38862848);            // 512 KB

  select_topk<<<M, 256, 0, stream>>>(keys, points, fc0_W, fc1_W, W0T, W1T, nidx);
  edge_prep<<<M / QPB, 256, 0, stream>>>(keys, points, feats, nidx,
                                         wc0_W, wc0_b, wc1_W, wc1_b, wc2_W, wc2_b,
                                         E);
  gemm_mfma<2048, true,  true,  true ><<<512, 256, 0, stream>>>(E, W0T, fc0_b, H16, 256);
  gemm_mfma<256,  false, false, false><<<dim3(M / 64, 2), 256, 0, stream>>>(H16, W1T, fc1_b, out, 128);
}

// Round 13
// 157.367 us; speedup vs baseline: 1.0153x; 1.0153x over previous
//
#include <hip/hip_runtime.h>
#include <cfloat>
#include <climits>

#define BATCH 4
#define KQ    2048
#define NP    4096
#define CIN   64
#define CMID  32
#define NB    16
#define NBINS 2048   // bits >> 20 : 8 exp bits + 3 mantissa bits
#define CANDCAP 256
#define QPB   8      // queries per block in edge_prep (2 sequential per wave)

typedef short   bf16x8  __attribute__((ext_vector_type(8)));
typedef float   floatx4 __attribute__((ext_vector_type(4)));

__device__ __forceinline__ unsigned short f2bf(float f) {
  unsigned u = __float_as_uint(f);
  u = (u + 0x7fffu + ((u >> 16) & 1u)) >> 16;   // RNE, inputs finite
  return (unsigned short)u;
}
__device__ __forceinline__ float bf2f(unsigned short u) {
  return __uint_as_float((unsigned)u << 16);
}

// async global->LDS, 16B per lane; LDS dst = base + lane*16 (wave-uniform base)
__device__ __forceinline__ void load_lds16(const void* g, void* l) {
  __builtin_amdgcn_global_load_lds(
      (const __attribute__((address_space(1))) unsigned int*)g,
      (__attribute__((address_space(3))) unsigned int*)l, 16, 0, 0);
}

// ---------------------------------------------------------------------------
// Kernel 1 (R27 = exact R25 revert, session best 157.6): block-per-query
// radix-select top-16, 32-lane parallel boundary refine. R26's transpose
// fold into blocks 0..543 regressed (+2.1 µs) — reverted. 8 KB u32 hist
// (2048 bins, bits>>20), two-level scan, rank pass. Set-only semantics;
// boundary ties -> lower index.
// ---------------------------------------------------------------------------
__global__ __launch_bounds__(256, 8) void select_topk(
    const float* __restrict__ keys, const float* __restrict__ points,
    int* __restrict__ nidx_g) {
  __shared__ __align__(16) int hist[NBINS];   // 8 KB
  __shared__ int   psum[256];
  __shared__ float cand_d[CANDCAP];
  __shared__ int   cand_i[CANDCAP];
  __shared__ int   nidx[NB];
  __shared__ int   sel_cnt, cand_cnt, sBin, sCbelow;

  const int tid = threadIdx.x;
  const int b   = blockIdx.x >> 11;

#pragma unroll
  for (int t = 0; t < 2; ++t)
    *reinterpret_cast<int4*>(&hist[(tid + t * 256) * 4]) = int4{0, 0, 0, 0};
  if (tid == 0) { sel_cnt = 0; cand_cnt = 0; }

  const float kx = keys[blockIdx.x * 3 + 0];
  const float ky = keys[blockIdx.x * 3 + 1];
  const float kz = keys[blockIdx.x * 3 + 2];
  __syncthreads();

  // distances in 4 chunks of 4 points (3 float4 live at a time) + histogram
  const float4* pv =
      reinterpret_cast<const float4*>(points + (size_t)b * NP * 3) + (size_t)tid * 12;
  float dreg[16];
#pragma unroll
  for (int g = 0; g < 4; ++g) {
    const float4 v0 = pv[g * 3 + 0];
    const float4 v1 = pv[g * 3 + 1];
    const float4 v2 = pv[g * 3 + 2];
    const float px[4] = {v0.x, v0.w, v1.z, v2.y};
    const float py[4] = {v0.y, v1.x, v1.w, v2.z};
    const float pz[4] = {v0.z, v1.y, v2.x, v2.w};
#pragma unroll
    for (int j = 0; j < 4; ++j) {
      const float dx = px[j] - kx, dy = py[j] - ky, dz = pz[j] - kz;
      const float d  = dx * dx + dy * dy + dz * dz;
      dreg[g * 4 + j] = d;
      atomicAdd(&hist[__float_as_uint(d) >> 20], 1);
    }
  }
  __syncthreads();

  // two-level threshold scan: per-thread 8-bin sums -> wave-0 shuffle scan
  {
    const int base = tid * 8;
    int s = 0;
#pragma unroll
    for (int t = 0; t < 2; ++t) {
      const int4 hv = *reinterpret_cast<const int4*>(&hist[base + t * 4]);
      s += hv.x + hv.y + hv.z + hv.w;
    }
    psum[tid] = s;
  }
  __syncthreads();

  if (tid < 64) {
    // group tid covers bins [tid*32, tid*32+32)
    const int q4 = psum[tid * 4] + psum[tid * 4 + 1] + psum[tid * 4 + 2] + psum[tid * 4 + 3];
    int incl = q4;
#pragma unroll
    for (int off = 1; off < 64; off <<= 1) {
      int u = __shfl_up(incl, off);
      if (tid >= off) incl += u;
    }
    const unsigned long long bal = __ballot(incl >= NB);
    const int bl = __ffsll((long long)bal) - 1;               // boundary group
    const int cum_before = __shfl(incl, bl) - __shfl(q4, bl); // cum before group

    // parallel refine: lanes 0..31 scan the group's 32 bins
    const int hv = (tid < 32) ? hist[bl * 32 + tid] : 0;
    int hincl = hv;
#pragma unroll
    for (int off = 1; off < 32; off <<= 1) {
      int u = __shfl_up(hincl, off);
      if (tid >= off) hincl += u;
    }
    const unsigned long long bal2 =
        __ballot(tid < 32 && (cum_before + hincl >= NB));
    const int bo = __ffsll((long long)bal2) - 1;
    if (tid == bo) {
      sBin = bl * 32 + bo;
      sCbelow = cum_before + hincl - hv;   // exclusive prefix at boundary bin
    }
  }
  __syncthreads();

  const unsigned B = (unsigned)sBin;
#pragma unroll
  for (int j = 0; j < 16; ++j) {
    const int i = tid * 16 + j;
    const unsigned bk = __float_as_uint(dreg[j]) >> 20;
    if (bk < B) {
      int pos = atomicAdd(&sel_cnt, 1);
      nidx[pos] = i;
    } else if (bk == B) {
      int pos = atomicAdd(&cand_cnt, 1);
      if (pos < CANDCAP) { cand_d[pos] = dreg[j]; cand_i[pos] = i; }
    }
  }
  __syncthreads();

  // boundary-bin rank pass: rank(j) = #{k: (d_k,i_k) < (d_j,i_j)}
  {
    const int rem = NB - sCbelow;
    const int cc  = min(cand_cnt, CANDCAP);
    for (int j = tid; j < cc; j += 256) {
      const float dj = cand_d[j]; const int ij = cand_i[j];
      int rank = 0;
      for (int k = 0; k < cc; ++k) {
        const float dk = cand_d[k]; const int ik = cand_i[k];
        rank += (dk < dj || (dk == dj && ik < ij)) ? 1 : 0;
      }
      if (rank < rem) nidx[sCbelow + rank] = ij;
    }
  }
  __syncthreads();

  if (tid < NB) nidx_g[blockIdx.x * NB + tid] = nidx[tid];
}

// ---------------------------------------------------------------------------
// Kernel 2 (R27 = exact R25): edge MLP + aggregation on MFMA, 2 queries per
// WAVE with `#pragma unroll 1` (full unroll regressed: VGPR pressure).
// B1/B2 weight fragments loaded once per wave. Per-query pipeline: h1 in
// A-frag layout, h2/m/e via 12 mfma_16x16x32, no block barriers in main
// path. Weight transposes folded into blocks 0..543 (R26's move into topk
// regressed — they overlap with topk's drain here).
// ---------------------------------------------------------------------------
__global__ __launch_bounds__(256) void edge_prep(
    const float* __restrict__ keys, const float* __restrict__ points,
    const float* __restrict__ feats, const int* __restrict__ nidx_g,
    const float* __restrict__ wc0_W, const float* __restrict__ wc0_b,
    const float* __restrict__ wc1_W, const float* __restrict__ wc1_b,
    const float* __restrict__ wc2_W, const float* __restrict__ wc2_b,
    const float* __restrict__ fc0_W, const float* __restrict__ fc1_W,
    unsigned short* __restrict__ W0T, unsigned short* __restrict__ W1T,
    unsigned short* __restrict__ E) {
  // per-wave slab: h2s [16][40 us] (80B rows) | ms [32][24 us] (48B rows)
  //              | fsT [64][24 us] (48B rows)  = 1280+1536+3072 = 5888 B
  __shared__ __align__(16) char smem[4 * 5888];   // 23 KB; tt aliases
  float (*tt)[33] = reinterpret_cast<float(*)[33]>(smem);

  const int tid = threadIdx.x;
  const int bid = blockIdx.x;
  const int q0  = bid * QPB;

  // ---- folded weight transposes (f32 [K][N] -> bf16 [N][K]) ----
  if (bid < 544) {
    const float* W; unsigned short* WT; int K, N, k0, n0;
    if (bid < 512) { W = fc0_W; WT = W0T; K = 2048; N = 256;
                     k0 = (bid >> 3) * 32; n0 = (bid & 7) * 32; }
    else           { W = fc1_W; WT = W1T; K = 256;  N = 128;
                     k0 = ((bid - 512) >> 2) * 32; n0 = ((bid - 512) & 3) * 32; }
    const int tx = tid & 31, ty = tid >> 5;
#pragma unroll
    for (int p = 0; p < 4; ++p)
      tt[ty + p * 8][tx] = W[(size_t)(k0 + ty + p * 8) * N + n0 + tx];
    __syncthreads();
#pragma unroll
    for (int p = 0; p < 4; ++p)
      WT[(size_t)(n0 + ty + p * 8) * K + k0 + tx] = f2bf(tt[tx][ty + p * 8]);
    __syncthreads();   // smem free again
  }

  const int wv   = tid >> 6, lane = tid & 63;
  const int s    = lane & 15, g = lane >> 4;

  unsigned short* h2s = reinterpret_cast<unsigned short*>(smem + wv * 5888);
  unsigned short* ms  = reinterpret_cast<unsigned short*>(smem + wv * 5888 + 1280);
  unsigned short* fsT = reinterpret_cast<unsigned short*>(smem + wv * 5888 + 2816);

  // ---- static B-fragments for W1, W2 (loaded once, reused for 2 queries) ----
  bf16x8 B1[2], B2[2];
#pragma unroll
  for (int t = 0; t < 2; ++t) {
#pragma unroll
    for (int e = 0; e < 8; ++e) {
      const int k = 8 * g + e, c = s + 16 * t;
      B1[t][e] = (short)f2bf(wc1_W[k * 32 + c]);
      B2[t][e] = (short)f2bf(wc2_W[k * 32 + c]);
    }
  }

  const floatx4 zc = {0.f, 0.f, 0.f, 0.f};

#pragma unroll 1
  for (int ep = 0; ep < 2; ++ep) {
    const int q = q0 + wv * 2 + ep;
    const int b = q >> 11;

    // ---- h1 (VALU, directly in A-frag layout) ----
    const int idx = nidx_g[q * NB + s];
    const float* p = points + ((size_t)b * NP + idx) * 3;
    const float kx = keys[q * 3], ky = keys[q * 3 + 1], kz = keys[q * 3 + 2];
    const float rx = p[0] - kx, ry = p[1] - ky, rz = p[2] - kz;
    bf16x8 A1;
#pragma unroll
    for (int e = 0; e < 8; ++e) {
      const int j = 8 * g + e;
      float h = rx * wc0_W[j] + ry * wc0_W[32 + j] + rz * wc0_W[64 + j] + wc0_b[j];
      A1[e] = (short)f2bf(fmaxf(h, 0.f));
    }

    // ---- h2 = relu(h1 @ W1 + b1) -> h2s[edge][j] (transpose via LDS) ----
#pragma unroll
    for (int t = 0; t < 2; ++t) {
      floatx4 d = __builtin_amdgcn_mfma_f32_16x16x32_bf16(A1, B1[t], zc, 0, 0, 0);
      const float bv = wc1_b[s + 16 * t];
#pragma unroll
      for (int r = 0; r < 4; ++r)
        h2s[(g * 4 + r) * 40 + 16 * t + s] = f2bf(fmaxf(d[r] + bv, 0.f));
    }

    // ---- A2 fragment: h2[edge=s][j=8g+e] ----
    const bf16x8 A2 = *reinterpret_cast<const bf16x8*>(&h2s[s * 40 + g * 8]);

    // ---- m = h2 @ W2 + b2 -> ms[mid][n] (packed b64) ----
#pragma unroll
    for (int t = 0; t < 2; ++t) {
      floatx4 d = __builtin_amdgcn_mfma_f32_16x16x32_bf16(A2, B2[t], zc, 0, 0, 0);
      const float bv = wc2_b[s + 16 * t];
      ushort4 o;
      o.x = f2bf(d[0] + bv); o.y = f2bf(d[1] + bv);
      o.z = f2bf(d[2] + bv); o.w = f2bf(d[3] + bv);
      *reinterpret_cast<ushort4*>(&ms[(16 * t + s) * 24 + g * 4]) = o;
    }

    // ---- stage neighbor features: fsT[ch][n] bf16 ----
#pragma unroll
    for (int t = 0; t < 4; ++t) {
      const int chunk = g + 4 * t;          // 0..15, ch0 = chunk*4
      const int n = s;
      const int idx_n = nidx_g[q * NB + n];
      const float4 v = *reinterpret_cast<const float4*>(
          feats + ((size_t)b * NP + idx_n) * CIN + chunk * 4);
      fsT[(chunk * 4 + 0) * 24 + n] = f2bf(v.x);
      fsT[(chunk * 4 + 1) * 24 + n] = f2bf(v.y);
      fsT[(chunk * 4 + 2) * 24 + n] = f2bf(v.z);
      fsT[(chunk * 4 + 3) * 24 + n] = f2bf(v.w);
    }

    // ---- e = f^T @ m : D[ch][mid], K=16 zero-padded to 32 ----
    bf16x8 fA[4], mB[2];
    const bf16x8 zf = {};
    if (lane < 32) {
#pragma unroll
      for (int ct = 0; ct < 4; ++ct)
        fA[ct] = *reinterpret_cast<const bf16x8*>(&fsT[(ct * 16 + s) * 24 + g * 8]);
#pragma unroll
      for (int mt = 0; mt < 2; ++mt)
        mB[mt] = *reinterpret_cast<const bf16x8*>(&ms[(mt * 16 + s) * 24 + g * 8]);
    } else {
#pragma unroll
      for (int ct = 0; ct < 4; ++ct) fA[ct] = zf;
#pragma unroll
      for (int mt = 0; mt < 2; ++mt) mB[mt] = zf;
    }

    unsigned short* Eq = E + (size_t)q * 2048;
#pragma unroll
    for (int mt = 0; mt < 2; ++mt) {
#pragma unroll
      for (int ct = 0; ct < 4; ++ct) {
        floatx4 d = __builtin_amdgcn_mfma_f32_16x16x32_bf16(fA[ct], mB[mt], zc, 0, 0, 0);
        ushort4 o;
        o.x = f2bf(d[0]); o.y = f2bf(d[1]); o.z = f2bf(d[2]); o.w = f2bf(d[3]);
        // mid = 16*mt + s (col), ch = 16*ct + 4*g + r (rows, contiguous)
        *reinterpret_cast<ushort4*>(&Eq[(16 * mt + s) * 64 + ct * 16 + g * 4]) = o;
      }
    }
  }
}

// ---------------------------------------------------------------------------
// Kernel 3/4: MFMA GEMM  C = act(A[M,KDIM]bf16 @ Bt[N,KDIM]^T + bias)
// 64x64 tile (4 waves x 32x32), BK=128, global_load_lds width-16 staging,
// XOR chunk swizzle for conflict-free ds_read_b128. SWIZZLE=true: an
// E-slab's 4 n-tiles land temporally adjacent on one XCD. R15: 2-phase
// double-buffered LDS; one barrier per K-iter.
// ---------------------------------------------------------------------------
template <int KDIM, bool RELU, bool OUTBF16, bool SWIZZLE>
__global__ __launch_bounds__(256) void gemm_mfma(
    const unsigned short* __restrict__ A,   // [M][KDIM] bf16
    const unsigned short* __restrict__ Bt,  // [N][KDIM] bf16
    const float* __restrict__ bias,
    void* __restrict__ Cout, int ldc) {
  __shared__ __align__(16) unsigned short Al[2][64 * 128];  // 32 KB
  __shared__ __align__(16) unsigned short Bl[2][64 * 128];  // 32 KB
  const int tid  = threadIdx.x;
  int m0, n0;
  if (SWIZZLE) {
    const int L    = blockIdx.x;
    const int slot = L >> 3;
    m0 = ((L & 7) * 16 + (slot >> 2)) * 64;
    n0 = (slot & 3) * 64;
  } else {
    m0 = blockIdx.x * 64;
    n0 = blockIdx.y * 64;
  }
  const int wv   = tid >> 6, lane = tid & 63;
  const int quad = lane >> 4, s = lane & 15;
  const int moff = (wv & 1) * 32, noff = (wv >> 1) * 32;
  const int lr   = lane >> 4, lc = lane & 15;

  floatx4 acc[2][2] = {{{0.f,0.f,0.f,0.f},{0.f,0.f,0.f,0.f}},
                       {{0.f,0.f,0.f,0.f},{0.f,0.f,0.f,0.f}}};

  auto stage = [&](int buf, int k0) {
#pragma unroll
    for (int t = 0; t < 4; ++t) {
      const int R0 = wv * 16 + t * 4;          // wave-uniform base row
      const int r  = R0 + lr;
      const int gc = lc ^ (r & 7);
      load_lds16(A  + (size_t)(m0 + r) * KDIM + k0 + gc * 8, &Al[buf][R0 * 128]);
      load_lds16(Bt + (size_t)(n0 + r) * KDIM + k0 + gc * 8, &Bl[buf][R0 * 128]);
    }
  };

  auto compute = [&](int buf) {
#pragma unroll
    for (int h = 0; h < 4; ++h) {
      bf16x8 af[2], bfr[2];
#pragma unroll
      for (int i = 0; i < 2; ++i) {
        const int r = moff + i * 16 + s;
        af[i] = *reinterpret_cast<const bf16x8*>(
            &Al[buf][(size_t)r * 128 + ((((h << 2) | quad) ^ (r & 7)) << 3)]);
      }
#pragma unroll
      for (int j = 0; j < 2; ++j) {
        const int r = noff + j * 16 + s;
        bfr[j] = *reinterpret_cast<const bf16x8*>(
            &Bl[buf][(size_t)r * 128 + ((((h << 2) | quad) ^ (r & 7)) << 3)]);
      }
#pragma unroll
      for (int i = 0; i < 2; ++i)
#pragma unroll
        for (int j = 0; j < 2; ++j)
          acc[i][j] = __builtin_amdgcn_mfma_f32_16x16x32_bf16(af[i], bfr[j], acc[i][j], 0, 0, 0);
    }
  };

  constexpr int NT = KDIM / 128;

  stage(0, 0);
  __syncthreads();
  int cur = 0;
#pragma unroll 1
  for (int it = 0; it < NT - 1; ++it) {
    stage(cur ^ 1, (it + 1) * 128);
    compute(cur);
    __syncthreads();
    cur ^= 1;
  }
  compute(cur);

#pragma unroll
  for (int i = 0; i < 2; ++i)
#pragma unroll
    for (int j = 0; j < 2; ++j) {
      const int col = n0 + noff + j * 16 + s;
      const float bv = bias[col];
#pragma unroll
      for (int r = 0; r < 4; ++r) {
        const int row = m0 + moff + i * 16 + quad * 4 + r;
        float v = acc[i][j][r] + bv;
        if (RELU) v = fmaxf(v, 0.f);
        if (OUTBF16)
          ((unsigned short*)Cout)[(size_t)row * ldc + col] = f2bf(v);
        else
          ((float*)Cout)[(size_t)row * ldc + col] = v;
      }
    }
}

// ---------------------------------------------------------------------------
extern "C" void kernel_launch(void* const* d_in, const int* in_sizes, int n_in,
                              void* d_out, int out_size, void* d_ws, size_t ws_size,
                              hipStream_t stream) {
  const float* keys   = (const float*)d_in[0];
  const float* points = (const float*)d_in[1];
  const float* feats  = (const float*)d_in[2];
  const float* wc0_W  = (const float*)d_in[3];
  const float* wc0_b  = (const float*)d_in[4];
  const float* wc1_W  = (const float*)d_in[5];
  const float* wc1_b  = (const float*)d_in[6];
  const float* wc2_W  = (const float*)d_in[7];
  const float* wc2_b  = (const float*)d_in[8];
  const float* fc0_W  = (const float*)d_in[9];
  const float* fc0_b  = (const float*)d_in[10];
  const float* fc1_W  = (const float*)d_in[11];
  const float* fc1_b  = (const float*)d_in[12];
  float* out = (float*)d_out;

  const int M = BATCH * KQ;   // 8192
  char* ws = (char*)d_ws;
  unsigned short* E    = (unsigned short*)(ws);                    // 32 MB
  unsigned short* H16  = (unsigned short*)(ws + (size_t)33554432); //  4 MB
  unsigned short* W0T  = (unsigned short*)(ws + (size_t)37748736); //  1 MB
  unsigned short* W1T  = (unsigned short*)(ws + (size_t)38797312); // 64 KB
  int*            nidx = (int*)(ws + (size_t)38862848);            // 512 KB

  select_topk<<<M, 256, 0, stream>>>(keys, points, nidx);
  edge_prep<<<M / QPB, 256, 0, stream>>>(keys, points, feats, nidx,
                                         wc0_W, wc0_b, wc1_W, wc1_b, wc2_W, wc2_b,
                                         fc0_W, fc1_W, W0T, W1T, E);
  gemm_mfma<2048, true,  true,  true ><<<512, 256, 0, stream>>>(E, W0T, fc0_b, H16, 256);
  gemm_mfma<256,  false, false, false><<<dim3(M / 64, 2), 256, 0, stream>>>(H16, W1T, fc1_b, out, 128);
}

// Round 14
// 156.855 us; speedup vs baseline: 1.0186x; 1.0033x over previous
//
#include <hip/hip_runtime.h>
#include <cfloat>
#include <climits>

#define BATCH 4
#define KQ    2048
#define NP    4096
#define CIN   64
#define CMID  32
#define NB    16
#define NBINS 2048   // bits >> 20 : 8 exp bits + 3 mantissa bits
#define CANDCAP 256
#define QPB   8      // queries per block in edge_prep (2 sequential per wave)

typedef short   bf16x8  __attribute__((ext_vector_type(8)));
typedef float   floatx4 __attribute__((ext_vector_type(4)));

__device__ __forceinline__ unsigned short f2bf(float f) {
  unsigned u = __float_as_uint(f);
  u = (u + 0x7fffu + ((u >> 16) & 1u)) >> 16;   // RNE, inputs finite
  return (unsigned short)u;
}
__device__ __forceinline__ float bf2f(unsigned short u) {
  return __uint_as_float((unsigned)u << 16);
}

// async global->LDS, 16B per lane; LDS dst = base + lane*16 (wave-uniform base)
__device__ __forceinline__ void load_lds16(const void* g, void* l) {
  __builtin_amdgcn_global_load_lds(
      (const __attribute__((address_space(1))) unsigned int*)g,
      (__attribute__((address_space(3))) unsigned int*)l, 16, 0, 0);
}

// ---------------------------------------------------------------------------
// Kernel 1 (R28 = R27 minus psum phase): block-per-query radix-select
// top-16. R28 change (monotone: strictly less work, same parallelism):
// wave-0 lanes sum their 32 bins DIRECTLY from hist via 8 bank-staggered
// int4 reads (4*((k+tid)&7) offset -> 8 lanes per 4-bank group = 2/bank,
// conflict-free), removing the psum[256] write+read round-trip, one
// __syncthreads, and 1 KB LDS. 32-lane parallel boundary refine (R25).
// 8 KB u32 hist (2048 bins, bits>>20), rank pass. Set-only semantics;
// boundary ties -> lower index.
// ---------------------------------------------------------------------------
__global__ __launch_bounds__(256, 8) void select_topk(
    const float* __restrict__ keys, const float* __restrict__ points,
    int* __restrict__ nidx_g) {
  __shared__ __align__(16) int hist[NBINS];   // 8 KB
  __shared__ float cand_d[CANDCAP];
  __shared__ int   cand_i[CANDCAP];
  __shared__ int   nidx[NB];
  __shared__ int   sel_cnt, cand_cnt, sBin, sCbelow;

  const int tid = threadIdx.x;
  const int b   = blockIdx.x >> 11;

#pragma unroll
  for (int t = 0; t < 2; ++t)
    *reinterpret_cast<int4*>(&hist[(tid + t * 256) * 4]) = int4{0, 0, 0, 0};
  if (tid == 0) { sel_cnt = 0; cand_cnt = 0; }

  const float kx = keys[blockIdx.x * 3 + 0];
  const float ky = keys[blockIdx.x * 3 + 1];
  const float kz = keys[blockIdx.x * 3 + 2];
  __syncthreads();

  // distances in 4 chunks of 4 points (3 float4 live at a time) + histogram
  const float4* pv =
      reinterpret_cast<const float4*>(points + (size_t)b * NP * 3) + (size_t)tid * 12;
  float dreg[16];
#pragma unroll
  for (int g = 0; g < 4; ++g) {
    const float4 v0 = pv[g * 3 + 0];
    const float4 v1 = pv[g * 3 + 1];
    const float4 v2 = pv[g * 3 + 2];
    const float px[4] = {v0.x, v0.w, v1.z, v2.y};
    const float py[4] = {v0.y, v1.x, v1.w, v2.z};
    const float pz[4] = {v0.z, v1.y, v2.x, v2.w};
#pragma unroll
    for (int j = 0; j < 4; ++j) {
      const float dx = px[j] - kx, dy = py[j] - ky, dz = pz[j] - kz;
      const float d  = dx * dx + dy * dy + dz * dz;
      dreg[g * 4 + j] = d;
      atomicAdd(&hist[__float_as_uint(d) >> 20], 1);
    }
  }
  __syncthreads();

  if (tid < 64) {
    // direct group sum: lane tid covers bins [tid*32, tid*32+32), read as
    // 8 int4s staggered by (k+tid)&7 -> 2 lanes/bank, conflict-free
    int q4 = 0;
#pragma unroll
    for (int k = 0; k < 8; ++k) {
      const int4 hv =
          *reinterpret_cast<const int4*>(&hist[tid * 32 + 4 * ((k + tid) & 7)]);
      q4 += hv.x + hv.y + hv.z + hv.w;
    }
    int incl = q4;
#pragma unroll
    for (int off = 1; off < 64; off <<= 1) {
      int u = __shfl_up(incl, off);
      if (tid >= off) incl += u;
    }
    const unsigned long long bal = __ballot(incl >= NB);
    const int bl = __ffsll((long long)bal) - 1;               // boundary group
    const int cum_before = __shfl(incl, bl) - __shfl(q4, bl); // cum before group

    // parallel refine: lanes 0..31 scan the group's 32 bins
    const int hv = (tid < 32) ? hist[bl * 32 + tid] : 0;
    int hincl = hv;
#pragma unroll
    for (int off = 1; off < 32; off <<= 1) {
      int u = __shfl_up(hincl, off);
      if (tid >= off) hincl += u;
    }
    const unsigned long long bal2 =
        __ballot(tid < 32 && (cum_before + hincl >= NB));
    const int bo = __ffsll((long long)bal2) - 1;
    if (tid == bo) {
      sBin = bl * 32 + bo;
      sCbelow = cum_before + hincl - hv;   // exclusive prefix at boundary bin
    }
  }
  __syncthreads();

  const unsigned B = (unsigned)sBin;
#pragma unroll
  for (int j = 0; j < 16; ++j) {
    const int i = tid * 16 + j;
    const unsigned bk = __float_as_uint(dreg[j]) >> 20;
    if (bk < B) {
      int pos = atomicAdd(&sel_cnt, 1);
      nidx[pos] = i;
    } else if (bk == B) {
      int pos = atomicAdd(&cand_cnt, 1);
      if (pos < CANDCAP) { cand_d[pos] = dreg[j]; cand_i[pos] = i; }
    }
  }
  __syncthreads();

  // boundary-bin rank pass: rank(j) = #{k: (d_k,i_k) < (d_j,i_j)}
  {
    const int rem = NB - sCbelow;
    const int cc  = min(cand_cnt, CANDCAP);
    for (int j = tid; j < cc; j += 256) {
      const float dj = cand_d[j]; const int ij = cand_i[j];
      int rank = 0;
      for (int k = 0; k < cc; ++k) {
        const float dk = cand_d[k]; const int ik = cand_i[k];
        rank += (dk < dj || (dk == dj && ik < ij)) ? 1 : 0;
      }
      if (rank < rem) nidx[sCbelow + rank] = ij;
    }
  }
  __syncthreads();

  if (tid < NB) nidx_g[blockIdx.x * NB + tid] = nidx[tid];
}

// ---------------------------------------------------------------------------
// Kernel 2 (R28 = R27/R25): edge MLP + aggregation on MFMA, 2 queries per
// WAVE with `#pragma unroll 1` (full unroll regressed: VGPR pressure).
// B1/B2 weight fragments loaded once per wave. Per-query pipeline: h1 in
// A-frag layout, h2/m/e via 12 mfma_16x16x32, no block barriers in main
// path. Weight transposes folded into blocks 0..543 (overlap with topk's
// drain; moving them into topk regressed — R26).
// ---------------------------------------------------------------------------
__global__ __launch_bounds__(256) void edge_prep(
    const float* __restrict__ keys, const float* __restrict__ points,
    const float* __restrict__ feats, const int* __restrict__ nidx_g,
    const float* __restrict__ wc0_W, const float* __restrict__ wc0_b,
    const float* __restrict__ wc1_W, const float* __restrict__ wc1_b,
    const float* __restrict__ wc2_W, const float* __restrict__ wc2_b,
    const float* __restrict__ fc0_W, const float* __restrict__ fc1_W,
    unsigned short* __restrict__ W0T, unsigned short* __restrict__ W1T,
    unsigned short* __restrict__ E) {
  // per-wave slab: h2s [16][40 us] (80B rows) | ms [32][24 us] (48B rows)
  //              | fsT [64][24 us] (48B rows)  = 1280+1536+3072 = 5888 B
  __shared__ __align__(16) char smem[4 * 5888];   // 23 KB; tt aliases
  float (*tt)[33] = reinterpret_cast<float(*)[33]>(smem);

  const int tid = threadIdx.x;
  const int bid = blockIdx.x;
  const int q0  = bid * QPB;

  // ---- folded weight transposes (f32 [K][N] -> bf16 [N][K]) ----
  if (bid < 544) {
    const float* W; unsigned short* WT; int K, N, k0, n0;
    if (bid < 512) { W = fc0_W; WT = W0T; K = 2048; N = 256;
                     k0 = (bid >> 3) * 32; n0 = (bid & 7) * 32; }
    else           { W = fc1_W; WT = W1T; K = 256;  N = 128;
                     k0 = ((bid - 512) >> 2) * 32; n0 = ((bid - 512) & 3) * 32; }
    const int tx = tid & 31, ty = tid >> 5;
#pragma unroll
    for (int p = 0; p < 4; ++p)
      tt[ty + p * 8][tx] = W[(size_t)(k0 + ty + p * 8) * N + n0 + tx];
    __syncthreads();
#pragma unroll
    for (int p = 0; p < 4; ++p)
      WT[(size_t)(n0 + ty + p * 8) * K + k0 + tx] = f2bf(tt[tx][ty + p * 8]);
    __syncthreads();   // smem free again
  }

  const int wv   = tid >> 6, lane = tid & 63;
  const int s    = lane & 15, g = lane >> 4;

  unsigned short* h2s = reinterpret_cast<unsigned short*>(smem + wv * 5888);
  unsigned short* ms  = reinterpret_cast<unsigned short*>(smem + wv * 5888 + 1280);
  unsigned short* fsT = reinterpret_cast<unsigned short*>(smem + wv * 5888 + 2816);

  // ---- static B-fragments for W1, W2 (loaded once, reused for 2 queries) ----
  bf16x8 B1[2], B2[2];
#pragma unroll
  for (int t = 0; t < 2; ++t) {
#pragma unroll
    for (int e = 0; e < 8; ++e) {
      const int k = 8 * g + e, c = s + 16 * t;
      B1[t][e] = (short)f2bf(wc1_W[k * 32 + c]);
      B2[t][e] = (short)f2bf(wc2_W[k * 32 + c]);
    }
  }

  const floatx4 zc = {0.f, 0.f, 0.f, 0.f};

#pragma unroll 1
  for (int ep = 0; ep < 2; ++ep) {
    const int q = q0 + wv * 2 + ep;
    const int b = q >> 11;

    // ---- h1 (VALU, directly in A-frag layout) ----
    const int idx = nidx_g[q * NB + s];
    const float* p = points + ((size_t)b * NP + idx) * 3;
    const float kx = keys[q * 3], ky = keys[q * 3 + 1], kz = keys[q * 3 + 2];
    const float rx = p[0] - kx, ry = p[1] - ky, rz = p[2] - kz;
    bf16x8 A1;
#pragma unroll
    for (int e = 0; e < 8; ++e) {
      const int j = 8 * g + e;
      float h = rx * wc0_W[j] + ry * wc0_W[32 + j] + rz * wc0_W[64 + j] + wc0_b[j];
      A1[e] = (short)f2bf(fmaxf(h, 0.f));
    }

    // ---- h2 = relu(h1 @ W1 + b1) -> h2s[edge][j] (transpose via LDS) ----
#pragma unroll
    for (int t = 0; t < 2; ++t) {
      floatx4 d = __builtin_amdgcn_mfma_f32_16x16x32_bf16(A1, B1[t], zc, 0, 0, 0);
      const float bv = wc1_b[s + 16 * t];
#pragma unroll
      for (int r = 0; r < 4; ++r)
        h2s[(g * 4 + r) * 40 + 16 * t + s] = f2bf(fmaxf(d[r] + bv, 0.f));
    }

    // ---- A2 fragment: h2[edge=s][j=8g+e] ----
    const bf16x8 A2 = *reinterpret_cast<const bf16x8*>(&h2s[s * 40 + g * 8]);

    // ---- m = h2 @ W2 + b2 -> ms[mid][n] (packed b64) ----
#pragma unroll
    for (int t = 0; t < 2; ++t) {
      floatx4 d = __builtin_amdgcn_mfma_f32_16x16x32_bf16(A2, B2[t], zc, 0, 0, 0);
      const float bv = wc2_b[s + 16 * t];
      ushort4 o;
      o.x = f2bf(d[0] + bv); o.y = f2bf(d[1] + bv);
      o.z = f2bf(d[2] + bv); o.w = f2bf(d[3] + bv);
      *reinterpret_cast<ushort4*>(&ms[(16 * t + s) * 24 + g * 4]) = o;
    }

    // ---- stage neighbor features: fsT[ch][n] bf16 ----
#pragma unroll
    for (int t = 0; t < 4; ++t) {
      const int chunk = g + 4 * t;          // 0..15, ch0 = chunk*4
      const int n = s;
      const int idx_n = nidx_g[q * NB + n];
      const float4 v = *reinterpret_cast<const float4*>(
          feats + ((size_t)b * NP + idx_n) * CIN + chunk * 4);
      fsT[(chunk * 4 + 0) * 24 + n] = f2bf(v.x);
      fsT[(chunk * 4 + 1) * 24 + n] = f2bf(v.y);
      fsT[(chunk * 4 + 2) * 24 + n] = f2bf(v.z);
      fsT[(chunk * 4 + 3) * 24 + n] = f2bf(v.w);
    }

    // ---- e = f^T @ m : D[ch][mid], K=16 zero-padded to 32 ----
    bf16x8 fA[4], mB[2];
    const bf16x8 zf = {};
    if (lane < 32) {
#pragma unroll
      for (int ct = 0; ct < 4; ++ct)
        fA[ct] = *reinterpret_cast<const bf16x8*>(&fsT[(ct * 16 + s) * 24 + g * 8]);
#pragma unroll
      for (int mt = 0; mt < 2; ++mt)
        mB[mt] = *reinterpret_cast<const bf16x8*>(&ms[(mt * 16 + s) * 24 + g * 8]);
    } else {
#pragma unroll
      for (int ct = 0; ct < 4; ++ct) fA[ct] = zf;
#pragma unroll
      for (int mt = 0; mt < 2; ++mt) mB[mt] = zf;
    }

    unsigned short* Eq = E + (size_t)q * 2048;
#pragma unroll
    for (int mt = 0; mt < 2; ++mt) {
#pragma unroll
      for (int ct = 0; ct < 4; ++ct) {
        floatx4 d = __builtin_amdgcn_mfma_f32_16x16x32_bf16(fA[ct], mB[mt], zc, 0, 0, 0);
        ushort4 o;
        o.x = f2bf(d[0]); o.y = f2bf(d[1]); o.z = f2bf(d[2]); o.w = f2bf(d[3]);
        // mid = 16*mt + s (col), ch = 16*ct + 4*g + r (rows, contiguous)
        *reinterpret_cast<ushort4*>(&Eq[(16 * mt + s) * 64 + ct * 16 + g * 4]) = o;
      }
    }
  }
}

// ---------------------------------------------------------------------------
// Kernel 3/4: MFMA GEMM  C = act(A[M,KDIM]bf16 @ Bt[N,KDIM]^T + bias)
// 64x64 tile (4 waves x 32x32), BK=128, global_load_lds width-16 staging,
// XOR chunk swizzle for conflict-free ds_read_b128. SWIZZLE=true: an
// E-slab's 4 n-tiles land temporally adjacent on one XCD. R15: 2-phase
// double-buffered LDS; one barrier per K-iter.
// ---------------------------------------------------------------------------
template <int KDIM, bool RELU, bool OUTBF16, bool SWIZZLE>
__global__ __launch_bounds__(256) void gemm_mfma(
    const unsigned short* __restrict__ A,   // [M][KDIM] bf16
    const unsigned short* __restrict__ Bt,  // [N][KDIM] bf16
    const float* __restrict__ bias,
    void* __restrict__ Cout, int ldc) {
  __shared__ __align__(16) unsigned short Al[2][64 * 128];  // 32 KB
  __shared__ __align__(16) unsigned short Bl[2][64 * 128];  // 32 KB
  const int tid  = threadIdx.x;
  int m0, n0;
  if (SWIZZLE) {
    const int L    = blockIdx.x;
    const int slot = L >> 3;
    m0 = ((L & 7) * 16 + (slot >> 2)) * 64;
    n0 = (slot & 3) * 64;
  } else {
    m0 = blockIdx.x * 64;
    n0 = blockIdx.y * 64;
  }
  const int wv   = tid >> 6, lane = tid & 63;
  const int quad = lane >> 4, s = lane & 15;
  const int moff = (wv & 1) * 32, noff = (wv >> 1) * 32;
  const int lr   = lane >> 4, lc = lane & 15;

  floatx4 acc[2][2] = {{{0.f,0.f,0.f,0.f},{0.f,0.f,0.f,0.f}},
                       {{0.f,0.f,0.f,0.f},{0.f,0.f,0.f,0.f}}};

  auto stage = [&](int buf, int k0) {
#pragma unroll
    for (int t = 0; t < 4; ++t) {
      const int R0 = wv * 16 + t * 4;          // wave-uniform base row
      const int r  = R0 + lr;
      const int gc = lc ^ (r & 7);
      load_lds16(A  + (size_t)(m0 + r) * KDIM + k0 + gc * 8, &Al[buf][R0 * 128]);
      load_lds16(Bt + (size_t)(n0 + r) * KDIM + k0 + gc * 8, &Bl[buf][R0 * 128]);
    }
  };

  auto compute = [&](int buf) {
#pragma unroll
    for (int h = 0; h < 4; ++h) {
      bf16x8 af[2], bfr[2];
#pragma unroll
      for (int i = 0; i < 2; ++i) {
        const int r = moff + i * 16 + s;
        af[i] = *reinterpret_cast<const bf16x8*>(
            &Al[buf][(size_t)r * 128 + ((((h << 2) | quad) ^ (r & 7)) << 3)]);
      }
#pragma unroll
      for (int j = 0; j < 2; ++j) {
        const int r = noff + j * 16 + s;
        bfr[j] = *reinterpret_cast<const bf16x8*>(
            &Bl[buf][(size_t)r * 128 + ((((h << 2) | quad) ^ (r & 7)) << 3)]);
      }
#pragma unroll
      for (int i = 0; i < 2; ++i)
#pragma unroll
        for (int j = 0; j < 2; ++j)
          acc[i][j] = __builtin_amdgcn_mfma_f32_16x16x32_bf16(af[i], bfr[j], acc[i][j], 0, 0, 0);
    }
  };

  constexpr int NT = KDIM / 128;

  stage(0, 0);
  __syncthreads();
  int cur = 0;
#pragma unroll 1
  for (int it = 0; it < NT - 1; ++it) {
    stage(cur ^ 1, (it + 1) * 128);
    compute(cur);
    __syncthreads();
    cur ^= 1;
  }
  compute(cur);

#pragma unroll
  for (int i = 0; i < 2; ++i)
#pragma unroll
    for (int j = 0; j < 2; ++j) {
      const int col = n0 + noff + j * 16 + s;
      const float bv = bias[col];
#pragma unroll
      for (int r = 0; r < 4; ++r) {
        const int row = m0 + moff + i * 16 + quad * 4 + r;
        float v = acc[i][j][r] + bv;
        if (RELU) v = fmaxf(v, 0.f);
        if (OUTBF16)
          ((unsigned short*)Cout)[(size_t)row * ldc + col] = f2bf(v);
        else
          ((float*)Cout)[(size_t)row * ldc + col] = v;
      }
    }
}

// ---------------------------------------------------------------------------
extern "C" void kernel_launch(void* const* d_in, const int* in_sizes, int n_in,
                              void* d_out, int out_size, void* d_ws, size_t ws_size,
                              hipStream_t stream) {
  const float* keys   = (const float*)d_in[0];
  const float* points = (const float*)d_in[1];
  const float* feats  = (const float*)d_in[2];
  const float* wc0_W  = (const float*)d_in[3];
  const float* wc0_b  = (const float*)d_in[4];
  const float* wc1_W  = (const float*)d_in[5];
  const float* wc1_b  = (const float*)d_in[6];
  const float* wc2_W  = (const float*)d_in[7];
  const float* wc2_b  = (const float*)d_in[8];
  const float* fc0_W  = (const float*)d_in[9];
  const float* fc0_b  = (const float*)d_in[10];
  const float* fc1_W  = (const float*)d_in[11];
  const float* fc1_b  = (const float*)d_in[12];
  float* out = (float*)d_out;

  const int M = BATCH * KQ;   // 8192
  char* ws = (char*)d_ws;
  unsigned short* E    = (unsigned short*)(ws);                    // 32 MB
  unsigned short* H16  = (unsigned short*)(ws + (size_t)33554432); //  4 MB
  unsigned short* W0T  = (unsigned short*)(ws + (size_t)37748736); //  1 MB
  unsigned short* W1T  = (unsigned short*)(ws + (size_t)38797312); // 64 KB
  int*            nidx = (int*)(ws + (size_t)38862848);            // 512 KB

  select_topk<<<M, 256, 0, stream>>>(keys, points, nidx);
  edge_prep<<<M / QPB, 256, 0, stream>>>(keys, points, feats, nidx,
                                         wc0_W, wc0_b, wc1_W, wc1_b, wc2_W, wc2_b,
                                         fc0_W, fc1_W, W0T, W1T, E);
  gemm_mfma<2048, true,  true,  true ><<<512, 256, 0, stream>>>(E, W0T, fc0_b, H16, 256);
  gemm_mfma<256,  false, false, false><<<dim3(M / 64, 2), 256, 0, stream>>>(H16, W1T, fc1_b, out, 128);
}